// Round 19
// baseline (67.779 us; speedup 1.0000x reference)
//
#include <hip/hip_runtime.h>

// GraphAttentionNet: x[8192,128] -> Q,K,V = relu(x W^T + b) [8192,64]
// out = softmax(Q K^T / 8) V + Q   (fp32 out)
//
// R19 = R17 pipeline with a WELL-FORMED register request:
// __launch_bounds__(512, 2) -> k = 2*4/(512/64) = exactly 1 block/CU,
// 2 waves/SIMD, 256-VGPR cap (HK attn's operating point, m243).
// R18's (512,1) was inconsistent (half a block/CU) and was IGNORED:
// VGPR stayed 128, 23MB spill writes remained. Single change this round.

typedef __attribute__((ext_vector_type(8))) __bf16 bf16x8;
typedef __attribute__((ext_vector_type(4))) float f32x4;
typedef __attribute__((ext_vector_type(16))) float f32x16;

constexpr int N_ROWS = 8192;
constexpr int CDIM   = 128;
constexpr int DKV    = 64;   // DK == DV == 64
constexpr int KVS    = 256;  // kv rows staged per chunk
constexpr float SCALE_Q = 0.125f * 1.4426950408889634f; // 1/sqrt(64) * log2(e)

__device__ __forceinline__ float fast_exp2(float x) {
    return __builtin_amdgcn_exp2f(x);   // v_exp_f32 (base-2)
}

__device__ __forceinline__ unsigned short f2bf(float x) {
    union { float f; unsigned u; } v; v.f = x;
    unsigned r = v.u + 0x7fffu + ((v.u >> 16) & 1u);   // RNE
    return (unsigned short)(r >> 16);
}

__device__ __forceinline__ float bf2f(unsigned short h) {
    union { unsigned u; float f; } v; v.u = (unsigned)h << 16; return v.f;
}

union Frag {
    unsigned u32[4];
    unsigned short u16[8];
    bf16x8 b;
    f32x4 f;
};

// ---------------------------------------------------------------- QKV ------
__global__ __launch_bounds__(128) void qkv_kernel(
    const float* __restrict__ x,
    const float* __restrict__ Wq, const float* __restrict__ bq,
    const float* __restrict__ Wk, const float* __restrict__ bk,
    const float* __restrict__ Wv, const float* __restrict__ bv,
    unsigned short* __restrict__ Qb, unsigned short* __restrict__ Kb,
    unsigned short* __restrict__ Vt, float* __restrict__ Qf)
{
    const int tid = threadIdx.x;
    const int w  = tid >> 6;       // wave 0..1
    const int l  = tid & 63;
    const int g  = l >> 4;         // lane quarter
    const int lm = l & 15;
    const int n_base = blockIdx.x * 32 + w * 16;

    bf16x8 af[4];
    {
        const float* xrow = x + (size_t)(n_base + lm) * CDIM;
        #pragma unroll
        for (int s = 0; s < 4; ++s) {
            f32x4 lo = *(const f32x4*)(xrow + s * 32 + g * 8);
            f32x4 hi = *(const f32x4*)(xrow + s * 32 + g * 8 + 4);
            Frag fr;
            #pragma unroll
            for (int j = 0; j < 4; ++j) { fr.u16[j] = f2bf(lo[j]); fr.u16[4 + j] = f2bf(hi[j]); }
            af[s] = fr.b;
        }
    }

    const float* Ws[3] = {Wq, Wk, Wv};
    const float* Bs[3] = {bq, bk, bv};
    #pragma unroll
    for (int mat = 0; mat < 3; ++mat) {
        #pragma unroll
        for (int ct = 0; ct < 4; ++ct) {
            const int f = ct * 16 + lm;                 // output feature (B col)
            const float* wrow = Ws[mat] + (size_t)f * CDIM;
            f32x4 acc = {0.f, 0.f, 0.f, 0.f};
            #pragma unroll
            for (int s = 0; s < 4; ++s) {
                f32x4 lo = *(const f32x4*)(wrow + s * 32 + g * 8);
                f32x4 hi = *(const f32x4*)(wrow + s * 32 + g * 8 + 4);
                Frag fr;
                #pragma unroll
                for (int j = 0; j < 4; ++j) { fr.u16[j] = f2bf(lo[j]); fr.u16[4 + j] = f2bf(hi[j]); }
                acc = __builtin_amdgcn_mfma_f32_16x16x32_bf16(af[s], fr.b, acc, 0, 0, 0);
            }
            const float bias = Bs[mat][f];
            #pragma unroll
            for (int j = 0; j < 4; ++j) {
                const int n = n_base + g * 4 + j;       // D row = A row
                const float v = fmaxf(acc[j] + bias, 0.f);
                if (mat == 0) {
                    Qf[(size_t)n * DKV + f] = v;
                    Qb[(size_t)n * DKV + f] = f2bf(v * SCALE_Q);
                } else if (mat == 1) {
                    Kb[(size_t)n * DKV + f] = f2bf(v);
                } else {
                    Vt[(size_t)f * N_ROWS + n] = f2bf(v); // store V transposed
                }
            }
        }
    }
}

// ---------------------------------------------------------- attention ------
// 8 waves/block (512 thr), q=32/wave -> 256 q/block. 32x32x16 MFMA.
// Whole kv chunk (KVS=256) staged once; 4 subtiles barrier-free,
// software-pipelined 2-deep: QK(kt+1) issued amid softmax/PV(kt).
// (512,2): exactly 1 block/CU, 2 waves/SIMD, 256-VGPR cap.
__global__ __launch_bounds__(512, 2) void attn_kernel(
    const unsigned short* __restrict__ Qb, const unsigned short* __restrict__ Kb,
    const unsigned short* __restrict__ Vt,
    unsigned short* __restrict__ PartOb, float* __restrict__ PartL,
    int nchunk)
{
    __shared__ __align__(16) unsigned short K_lds[KVS * DKV];   // 32 KB
    __shared__ __align__(16) unsigned short V_lds[DKV * KVS];   // 32 KB

    const int tid = threadIdx.x;
    const int w  = tid >> 6;       // wave 0..7
    const int l  = tid & 63;
    const int c  = l & 31;         // q column / A-row
    const int hB = l >> 5;         // lane half (k-subgroup)
    const int qb = blockIdx.x;
    const int sp = blockIdx.y;
    const int q0 = qb * 256 + w * 32;

    // Hoisted Q B-fragments: B[k][col=q] = Q[q0+c][16ks + 8hB + j]
    bf16x8 qf0, qf1, qf2, qf3;
    {
        const unsigned short* qp = Qb + (size_t)(q0 + c) * DKV + hB * 8;
        qf0 = *(const bf16x8*)(qp);
        qf1 = *(const bf16x8*)(qp + 16);
        qf2 = *(const bf16x8*)(qp + 32);
        qf3 = *(const bf16x8*)(qp + 48);
    }

    f32x16 o0 = {}, o1 = {};
    float lsum = 0.f;

    const int swzK = ((c & 7) ^ (((c >> 3) & 3) << 1)) << 4;   // byte XOR

    // pipeline state: parity-indexed score regs (compile-time after unroll)
    f32x16 sA[2], sB[2];
    bf16x8 kfr0[4], kfr1[4];   // transient K frags of the NEXT subtile

#define LDK(KT) do { \
    const char* Kp_ = (const char*)K_lds + (size_t)(KT) * 64 * 128; \
    _Pragma("unroll") \
    for (int ks = 0; ks < 4; ++ks) { \
        const int cb_ = ks * 32 + hB * 16; \
        kfr0[ks] = *(const bf16x8*)(Kp_ + c * 128 + (cb_ ^ swzK)); \
        kfr1[ks] = *(const bf16x8*)(Kp_ + (32 + c) * 128 + (cb_ ^ swzK)); \
    } \
} while (0)

#define QKSTEP(P) do { \
    f32x16 z_ = {}; \
    sA[P] = z_; sB[P] = z_; \
    _Pragma("unroll") \
    for (int ks = 0; ks < 4; ++ks) { \
        const bf16x8 qv_ = (ks == 0) ? qf0 : (ks == 1) ? qf1 : (ks == 2) ? qf2 : qf3; \
        sA[P] = __builtin_amdgcn_mfma_f32_32x32x16_bf16(kfr0[ks], qv_, sA[P], 0, 0, 0); \
        sB[P] = __builtin_amdgcn_mfma_f32_32x32x16_bf16(kfr1[ks], qv_, sB[P], 0, 0, 0); \
    } \
} while (0)

    for (int ch = 0; ch < nchunk; ++ch) {
        const int kv0 = (sp * nchunk + ch) * KVS;
        if (ch > 0) __syncthreads();   // all waves done before re-staging

        // ---- Prologue staging: 4 x (K + V) global_load_lds per thread ----
        #pragma unroll
        for (int i = 0; i < 4; ++i) {
            const int rk = w * 8 + (l >> 3) + 64 * i;           // 0..255
            const int sk = ((l & 7) ^ ((rk & 7) ^ (((rk >> 3) & 3) << 1))) * 8;
            __builtin_amdgcn_global_load_lds(
                (const __attribute__((address_space(1))) unsigned int*)(Kb + (size_t)(kv0 + rk) * DKV + sk),
                (__attribute__((address_space(3))) unsigned int*)&K_lds[i * 4096 + w * 512], 16, 0, 0);
            const int rv = w * 2 + (l >> 5) + 16 * i;           // 0..63
            const int sv = ((l & 31) ^ (rv & 31)) * 8;
            __builtin_amdgcn_global_load_lds(
                (const __attribute__((address_space(1))) unsigned int*)(Vt + (size_t)rv * N_ROWS + kv0 + sv),
                (__attribute__((address_space(3))) unsigned int*)&V_lds[i * 4096 + w * 512], 16, 0, 0);
        }
        __syncthreads();   // implicit vmcnt(0): both tiles resident

        // ---- pipeline prologue: K frags + QK of subtile 0 ----
        LDK(0);
        QKSTEP(0);

        // ---- 2-deep pipelined subtiles (fully unrolled; parity regs) ----
        #pragma unroll
        for (int kt = 0; kt < 4; ++kt) {
            const int P  = kt & 1;
            const int PN = (kt + 1) & 1;

            // (a) issue next subtile's K-fragment loads (DS)
            if (kt < 3) LDK(kt + 1);

            // (b) softmax of current subtile (VALU/TRANS; indep of (a))
            unsigned pk[16];
            float ls = 0.f;
            #pragma unroll
            for (int p = 0; p < 8; ++p) {
                float a = fast_exp2(sA[P][2 * p]);
                float b = fast_exp2(sA[P][2 * p + 1]);
                ls += a + b;
                union { unsigned u; __bf16 h[2]; } uu;
                uu.h[0] = (__bf16)a; uu.h[1] = (__bf16)b;
                pk[p] = uu.u;
            }
            #pragma unroll
            for (int p = 0; p < 8; ++p) {
                float a = fast_exp2(sB[P][2 * p]);
                float b = fast_exp2(sB[P][2 * p + 1]);
                ls += a + b;
                union { unsigned u; __bf16 h[2]; } uu;
                uu.h[0] = (__bf16)a; uu.h[1] = (__bf16)b;
                pk[8 + p] = uu.u;
            }
            lsum += ls;

            // (c) next subtile's QK^T (MFMA; indep of (b), waits only on (a))
            if (kt < 3) QKSTEP(PN);

            // (d) current subtile's PV: V frags (DS) + shuffles + MFMA
            #pragma unroll
            for (int ks = 0; ks < 4; ++ks) {
                const int base = (ks >> 1) * 8 + (ks & 1) * 4;
                const unsigned ownA  = hB ? pk[base + 2] : pk[base + 0];
                const unsigned ownB  = hB ? pk[base + 3] : pk[base + 1];
                const unsigned contA = hB ? pk[base + 0] : pk[base + 2];
                const unsigned contB = hB ? pk[base + 1] : pk[base + 3];
                const unsigned crossA = __shfl_xor(contA, 32);
                const unsigned crossB = __shfl_xor(contB, 32);
                Frag pf;
                pf.u32[0] = hB ? crossA : ownA;
                pf.u32[1] = hB ? crossB : ownB;
                pf.u32[2] = hB ? ownA : crossA;
                pf.u32[3] = hB ? ownB : crossB;
                const int sl = (kt * 8 + ks * 2 + hB) ^ c;      // V slot (16B)
                bf16x8 v0 = *(const bf16x8*)((const char*)V_lds + c * 512 + sl * 16);
                bf16x8 v1 = *(const bf16x8*)((const char*)V_lds + (32 + c) * 512 + sl * 16);
                o0 = __builtin_amdgcn_mfma_f32_32x32x16_bf16(v0, pf.b, o0, 0, 0, 0);
                o1 = __builtin_amdgcn_mfma_f32_32x32x16_bf16(v1, pf.b, o1, 0, 0, 0);
            }
        }
    }
#undef LDK
#undef QKSTEP

    lsum += __shfl_xor(lsum, 32);             // combine the two kv half-sums

    // O^T[dv][q] -> PartOb bf16 [sp][q][dv], packed 8B stores.
    {
        unsigned short* po = PartOb + ((size_t)sp * N_ROWS + q0 + c) * 64;
        #pragma unroll
        for (int rq = 0; rq < 4; ++rq) {
            union { unsigned u[2]; __bf16 h[4]; } pa, pb;
            #pragma unroll
            for (int j = 0; j < 4; ++j) { pa.h[j] = (__bf16)o0[4 * rq + j]; pb.h[j] = (__bf16)o1[4 * rq + j]; }
            *(uint2*)(po + 8 * rq + 4 * hB)      = *(uint2*)pa.u;
            *(uint2*)(po + 32 + 8 * rq + 4 * hB) = *(uint2*)pb.u;
        }
    }
    if (hB == 0)
        PartL[(size_t)sp * N_ROWS + q0 + c] = lsum;
}

// -------------------------------------------------------------- merge ------
__global__ __launch_bounds__(256) void merge_kernel(
    const unsigned short* __restrict__ PartOb, const float* __restrict__ PartL,
    const float* __restrict__ Qf, float* __restrict__ out, int split)
{
    const int gid = blockIdx.x * 256 + threadIdx.x;   // 0 .. 8192*32-1
    const int q  = gid >> 5;
    const int dp = gid & 31;          // dv pair index

    float L = 0.f, a0 = 0.f, a1 = 0.f;
    for (int s = 0; s < split; ++s) {
        L += PartL[(size_t)s * N_ROWS + q];
        const unsigned v = *(const unsigned*)(PartOb + ((size_t)s * N_ROWS + q) * 64 + 2 * dp);
        a0 += bf2f((unsigned short)(v & 0xffffu));
        a1 += bf2f((unsigned short)(v >> 16));
    }
    const float invL = 1.f / L;
    const int d0 = 2 * dp;
    out[(size_t)q * 64 + d0]     = a0 * invL + Qf[(size_t)q * 64 + d0];
    out[(size_t)q * 64 + d0 + 1] = a1 * invL + Qf[(size_t)q * 64 + d0 + 1];
}

// ------------------------------------------------------------- launch ------
extern "C" void kernel_launch(void* const* d_in, const int* in_sizes, int n_in,
                              void* d_out, int out_size, void* d_ws, size_t ws_size,
                              hipStream_t stream)
{
    const float* x  = (const float*)d_in[0];
    const float* Wq = (const float*)d_in[1];
    const float* bq = (const float*)d_in[2];
    const float* Wk = (const float*)d_in[3];
    const float* bk = (const float*)d_in[4];
    const float* Wv = (const float*)d_in[5];
    const float* bv = (const float*)d_in[6];
    float* out = (float*)d_out;

    char* ws = (char*)d_ws;
    size_t off = 0;
    auto take = [&](size_t bytes) {
        char* p = ws + off;
        off += (bytes + 255) & ~(size_t)255;
        return p;
    };
    unsigned short* Qb = (unsigned short*)take((size_t)N_ROWS * DKV * 2);
    unsigned short* Kb = (unsigned short*)take((size_t)N_ROWS * DKV * 2);
    unsigned short* Vt = (unsigned short*)take((size_t)DKV * N_ROWS * 2);
    float*          Qf = (float*)take((size_t)N_ROWS * DKV * 4);

    // split=16, 512 kv per block = 2 chunks of KVS=256.
    int split = 16, nchunk = 2;
    const size_t per_split = (size_t)N_ROWS * 64 * 2 + (size_t)N_ROWS * 4 + 512;
    while (split > 1 && off + (size_t)split * per_split > ws_size) { split >>= 1; nchunk <<= 1; }

    unsigned short* PartOb = (unsigned short*)take((size_t)split * N_ROWS * 64 * 2);
    float*          PartL  = (float*)take((size_t)split * N_ROWS * 4);

    qkv_kernel<<<dim3(N_ROWS / 32), dim3(128), 0, stream>>>(
        x, Wq, bq, Wk, bk, Wv, bv, Qb, Kb, Vt, Qf);
    attn_kernel<<<dim3(N_ROWS / 256, split), dim3(512), 0, stream>>>(
        Qb, Kb, Vt, PartOb, PartL, nchunk);
    merge_kernel<<<dim3(N_ROWS * 32 / 256), dim3(256), 0, stream>>>(
        PartOb, PartL, Qf, out, split);
}

// Round 20
// 53.777 us; speedup vs baseline: 1.2604x; 1.2604x over previous
//
#include <hip/hip_runtime.h>

// GraphAttentionNet: x[8192,128] -> Q,K,V = relu(x W^T + b) [8192,64]
// out = softmax(Q K^T / 8) V + Q   (fp32 out)
//
// R20 = R17 pipeline with amdgpu_waves_per_eu(2,2) PINNED (min AND max).
// R18/R19 showed __launch_bounds__'s 2nd arg only sets the MIN waves/EU;
// the allocator still targets max-achievable occupancy (LDS allows 4/EU)
// and keeps the 128-VGPR cap, spilling 23MB/dispatch. Pinning max=2
// grants the 256-VGPR budget so the pipeline state fits spill-free.

typedef __attribute__((ext_vector_type(8))) __bf16 bf16x8;
typedef __attribute__((ext_vector_type(4))) float f32x4;
typedef __attribute__((ext_vector_type(16))) float f32x16;

constexpr int N_ROWS = 8192;
constexpr int CDIM   = 128;
constexpr int DKV    = 64;   // DK == DV == 64
constexpr int KVS    = 256;  // kv rows staged per chunk
constexpr float SCALE_Q = 0.125f * 1.4426950408889634f; // 1/sqrt(64) * log2(e)

__device__ __forceinline__ float fast_exp2(float x) {
    return __builtin_amdgcn_exp2f(x);   // v_exp_f32 (base-2)
}

__device__ __forceinline__ unsigned short f2bf(float x) {
    union { float f; unsigned u; } v; v.f = x;
    unsigned r = v.u + 0x7fffu + ((v.u >> 16) & 1u);   // RNE
    return (unsigned short)(r >> 16);
}

__device__ __forceinline__ float bf2f(unsigned short h) {
    union { unsigned u; float f; } v; v.u = (unsigned)h << 16; return v.f;
}

union Frag {
    unsigned u32[4];
    unsigned short u16[8];
    bf16x8 b;
    f32x4 f;
};

// ---------------------------------------------------------------- QKV ------
__global__ __launch_bounds__(128) void qkv_kernel(
    const float* __restrict__ x,
    const float* __restrict__ Wq, const float* __restrict__ bq,
    const float* __restrict__ Wk, const float* __restrict__ bk,
    const float* __restrict__ Wv, const float* __restrict__ bv,
    unsigned short* __restrict__ Qb, unsigned short* __restrict__ Kb,
    unsigned short* __restrict__ Vt, float* __restrict__ Qf)
{
    const int tid = threadIdx.x;
    const int w  = tid >> 6;       // wave 0..1
    const int l  = tid & 63;
    const int g  = l >> 4;         // lane quarter
    const int lm = l & 15;
    const int n_base = blockIdx.x * 32 + w * 16;

    bf16x8 af[4];
    {
        const float* xrow = x + (size_t)(n_base + lm) * CDIM;
        #pragma unroll
        for (int s = 0; s < 4; ++s) {
            f32x4 lo = *(const f32x4*)(xrow + s * 32 + g * 8);
            f32x4 hi = *(const f32x4*)(xrow + s * 32 + g * 8 + 4);
            Frag fr;
            #pragma unroll
            for (int j = 0; j < 4; ++j) { fr.u16[j] = f2bf(lo[j]); fr.u16[4 + j] = f2bf(hi[j]); }
            af[s] = fr.b;
        }
    }

    const float* Ws[3] = {Wq, Wk, Wv};
    const float* Bs[3] = {bq, bk, bv};
    #pragma unroll
    for (int mat = 0; mat < 3; ++mat) {
        #pragma unroll
        for (int ct = 0; ct < 4; ++ct) {
            const int f = ct * 16 + lm;                 // output feature (B col)
            const float* wrow = Ws[mat] + (size_t)f * CDIM;
            f32x4 acc = {0.f, 0.f, 0.f, 0.f};
            #pragma unroll
            for (int s = 0; s < 4; ++s) {
                f32x4 lo = *(const f32x4*)(wrow + s * 32 + g * 8);
                f32x4 hi = *(const f32x4*)(wrow + s * 32 + g * 8 + 4);
                Frag fr;
                #pragma unroll
                for (int j = 0; j < 4; ++j) { fr.u16[j] = f2bf(lo[j]); fr.u16[4 + j] = f2bf(hi[j]); }
                acc = __builtin_amdgcn_mfma_f32_16x16x32_bf16(af[s], fr.b, acc, 0, 0, 0);
            }
            const float bias = Bs[mat][f];
            #pragma unroll
            for (int j = 0; j < 4; ++j) {
                const int n = n_base + g * 4 + j;       // D row = A row
                const float v = fmaxf(acc[j] + bias, 0.f);
                if (mat == 0) {
                    Qf[(size_t)n * DKV + f] = v;
                    Qb[(size_t)n * DKV + f] = f2bf(v * SCALE_Q);
                } else if (mat == 1) {
                    Kb[(size_t)n * DKV + f] = f2bf(v);
                } else {
                    Vt[(size_t)f * N_ROWS + n] = f2bf(v); // store V transposed
                }
            }
        }
    }
}

// ---------------------------------------------------------- attention ------
// 8 waves/block (512 thr), q=32/wave -> 256 q/block. 32x32x16 MFMA.
// Whole kv chunk (KVS=256) staged once; 4 subtiles barrier-free,
// software-pipelined 2-deep: QK(kt+1) issued amid softmax/PV(kt).
// waves_per_eu(2,2): occupancy pinned to 2 waves/EU -> 256-VGPR budget.
__global__ __launch_bounds__(512) __attribute__((amdgpu_waves_per_eu(2, 2)))
void attn_kernel(
    const unsigned short* __restrict__ Qb, const unsigned short* __restrict__ Kb,
    const unsigned short* __restrict__ Vt,
    unsigned short* __restrict__ PartOb, float* __restrict__ PartL,
    int nchunk)
{
    __shared__ __align__(16) unsigned short K_lds[KVS * DKV];   // 32 KB
    __shared__ __align__(16) unsigned short V_lds[DKV * KVS];   // 32 KB

    const int tid = threadIdx.x;
    const int w  = tid >> 6;       // wave 0..7
    const int l  = tid & 63;
    const int c  = l & 31;         // q column / A-row
    const int hB = l >> 5;         // lane half (k-subgroup)
    const int qb = blockIdx.x;
    const int sp = blockIdx.y;
    const int q0 = qb * 256 + w * 32;

    // Hoisted Q B-fragments: B[k][col=q] = Q[q0+c][16ks + 8hB + j]
    bf16x8 qf0, qf1, qf2, qf3;
    {
        const unsigned short* qp = Qb + (size_t)(q0 + c) * DKV + hB * 8;
        qf0 = *(const bf16x8*)(qp);
        qf1 = *(const bf16x8*)(qp + 16);
        qf2 = *(const bf16x8*)(qp + 32);
        qf3 = *(const bf16x8*)(qp + 48);
    }

    f32x16 o0 = {}, o1 = {};
    float lsum = 0.f;

    const int swzK = ((c & 7) ^ (((c >> 3) & 3) << 1)) << 4;   // byte XOR

    // pipeline state: parity-indexed score regs (compile-time after unroll)
    f32x16 sA[2], sB[2];
    bf16x8 kfr0[4], kfr1[4];   // transient K frags of the NEXT subtile

#define LDK(KT) do { \
    const char* Kp_ = (const char*)K_lds + (size_t)(KT) * 64 * 128; \
    _Pragma("unroll") \
    for (int ks = 0; ks < 4; ++ks) { \
        const int cb_ = ks * 32 + hB * 16; \
        kfr0[ks] = *(const bf16x8*)(Kp_ + c * 128 + (cb_ ^ swzK)); \
        kfr1[ks] = *(const bf16x8*)(Kp_ + (32 + c) * 128 + (cb_ ^ swzK)); \
    } \
} while (0)

#define QKSTEP(P) do { \
    f32x16 z_ = {}; \
    sA[P] = z_; sB[P] = z_; \
    _Pragma("unroll") \
    for (int ks = 0; ks < 4; ++ks) { \
        const bf16x8 qv_ = (ks == 0) ? qf0 : (ks == 1) ? qf1 : (ks == 2) ? qf2 : qf3; \
        sA[P] = __builtin_amdgcn_mfma_f32_32x32x16_bf16(kfr0[ks], qv_, sA[P], 0, 0, 0); \
        sB[P] = __builtin_amdgcn_mfma_f32_32x32x16_bf16(kfr1[ks], qv_, sB[P], 0, 0, 0); \
    } \
} while (0)

    for (int ch = 0; ch < nchunk; ++ch) {
        const int kv0 = (sp * nchunk + ch) * KVS;
        if (ch > 0) __syncthreads();   // all waves done before re-staging

        // ---- Prologue staging: 4 x (K + V) global_load_lds per thread ----
        #pragma unroll
        for (int i = 0; i < 4; ++i) {
            const int rk = w * 8 + (l >> 3) + 64 * i;           // 0..255
            const int sk = ((l & 7) ^ ((rk & 7) ^ (((rk >> 3) & 3) << 1))) * 8;
            __builtin_amdgcn_global_load_lds(
                (const __attribute__((address_space(1))) unsigned int*)(Kb + (size_t)(kv0 + rk) * DKV + sk),
                (__attribute__((address_space(3))) unsigned int*)&K_lds[i * 4096 + w * 512], 16, 0, 0);
            const int rv = w * 2 + (l >> 5) + 16 * i;           // 0..63
            const int sv = ((l & 31) ^ (rv & 31)) * 8;
            __builtin_amdgcn_global_load_lds(
                (const __attribute__((address_space(1))) unsigned int*)(Vt + (size_t)rv * N_ROWS + kv0 + sv),
                (__attribute__((address_space(3))) unsigned int*)&V_lds[i * 4096 + w * 512], 16, 0, 0);
        }
        __syncthreads();   // implicit vmcnt(0): both tiles resident

        // ---- pipeline prologue: K frags + QK of subtile 0 ----
        LDK(0);
        QKSTEP(0);

        // ---- 2-deep pipelined subtiles (fully unrolled; parity regs) ----
        #pragma unroll
        for (int kt = 0; kt < 4; ++kt) {
            const int P  = kt & 1;
            const int PN = (kt + 1) & 1;

            // (a) issue next subtile's K-fragment loads (DS)
            if (kt < 3) LDK(kt + 1);

            // (b) softmax of current subtile (VALU/TRANS; indep of (a))
            unsigned pk[16];
            float ls = 0.f;
            #pragma unroll
            for (int p = 0; p < 8; ++p) {
                float a = fast_exp2(sA[P][2 * p]);
                float b = fast_exp2(sA[P][2 * p + 1]);
                ls += a + b;
                union { unsigned u; __bf16 h[2]; } uu;
                uu.h[0] = (__bf16)a; uu.h[1] = (__bf16)b;
                pk[p] = uu.u;
            }
            #pragma unroll
            for (int p = 0; p < 8; ++p) {
                float a = fast_exp2(sB[P][2 * p]);
                float b = fast_exp2(sB[P][2 * p + 1]);
                ls += a + b;
                union { unsigned u; __bf16 h[2]; } uu;
                uu.h[0] = (__bf16)a; uu.h[1] = (__bf16)b;
                pk[8 + p] = uu.u;
            }
            lsum += ls;

            // (c) next subtile's QK^T (MFMA; indep of (b), waits only on (a))
            if (kt < 3) QKSTEP(PN);

            // (d) current subtile's PV: V frags (DS) + shuffles + MFMA
            #pragma unroll
            for (int ks = 0; ks < 4; ++ks) {
                const int base = (ks >> 1) * 8 + (ks & 1) * 4;
                const unsigned ownA  = hB ? pk[base + 2] : pk[base + 0];
                const unsigned ownB  = hB ? pk[base + 3] : pk[base + 1];
                const unsigned contA = hB ? pk[base + 0] : pk[base + 2];
                const unsigned contB = hB ? pk[base + 1] : pk[base + 3];
                const unsigned crossA = __shfl_xor(contA, 32);
                const unsigned crossB = __shfl_xor(contB, 32);
                Frag pf;
                pf.u32[0] = hB ? crossA : ownA;
                pf.u32[1] = hB ? crossB : ownB;
                pf.u32[2] = hB ? ownA : crossA;
                pf.u32[3] = hB ? ownB : crossB;
                const int sl = (kt * 8 + ks * 2 + hB) ^ c;      // V slot (16B)
                bf16x8 v0 = *(const bf16x8*)((const char*)V_lds + c * 512 + sl * 16);
                bf16x8 v1 = *(const bf16x8*)((const char*)V_lds + (32 + c) * 512 + sl * 16);
                o0 = __builtin_amdgcn_mfma_f32_32x32x16_bf16(v0, pf.b, o0, 0, 0, 0);
                o1 = __builtin_amdgcn_mfma_f32_32x32x16_bf16(v1, pf.b, o1, 0, 0, 0);
            }
        }
    }
#undef LDK
#undef QKSTEP

    lsum += __shfl_xor(lsum, 32);             // combine the two kv half-sums

    // O^T[dv][q] -> PartOb bf16 [sp][q][dv], packed 8B stores.
    {
        unsigned short* po = PartOb + ((size_t)sp * N_ROWS + q0 + c) * 64;
        #pragma unroll
        for (int rq = 0; rq < 4; ++rq) {
            union { unsigned u[2]; __bf16 h[4]; } pa, pb;
            #pragma unroll
            for (int j = 0; j < 4; ++j) { pa.h[j] = (__bf16)o0[4 * rq + j]; pb.h[j] = (__bf16)o1[4 * rq + j]; }
            *(uint2*)(po + 8 * rq + 4 * hB)      = *(uint2*)pa.u;
            *(uint2*)(po + 32 + 8 * rq + 4 * hB) = *(uint2*)pb.u;
        }
    }
    if (hB == 0)
        PartL[(size_t)sp * N_ROWS + q0 + c] = lsum;
}

// -------------------------------------------------------------- merge ------
__global__ __launch_bounds__(256) void merge_kernel(
    const unsigned short* __restrict__ PartOb, const float* __restrict__ PartL,
    const float* __restrict__ Qf, float* __restrict__ out, int split)
{
    const int gid = blockIdx.x * 256 + threadIdx.x;   // 0 .. 8192*32-1
    const int q  = gid >> 5;
    const int dp = gid & 31;          // dv pair index

    float L = 0.f, a0 = 0.f, a1 = 0.f;
    for (int s = 0; s < split; ++s) {
        L += PartL[(size_t)s * N_ROWS + q];
        const unsigned v = *(const unsigned*)(PartOb + ((size_t)s * N_ROWS + q) * 64 + 2 * dp);
        a0 += bf2f((unsigned short)(v & 0xffffu));
        a1 += bf2f((unsigned short)(v >> 16));
    }
    const float invL = 1.f / L;
    const int d0 = 2 * dp;
    out[(size_t)q * 64 + d0]     = a0 * invL + Qf[(size_t)q * 64 + d0];
    out[(size_t)q * 64 + d0 + 1] = a1 * invL + Qf[(size_t)q * 64 + d0 + 1];
}

// ------------------------------------------------------------- launch ------
extern "C" void kernel_launch(void* const* d_in, const int* in_sizes, int n_in,
                              void* d_out, int out_size, void* d_ws, size_t ws_size,
                              hipStream_t stream)
{
    const float* x  = (const float*)d_in[0];
    const float* Wq = (const float*)d_in[1];
    const float* bq = (const float*)d_in[2];
    const float* Wk = (const float*)d_in[3];
    const float* bk = (const float*)d_in[4];
    const float* Wv = (const float*)d_in[5];
    const float* bv = (const float*)d_in[6];
    float* out = (float*)d_out;

    char* ws = (char*)d_ws;
    size_t off = 0;
    auto take = [&](size_t bytes) {
        char* p = ws + off;
        off += (bytes + 255) & ~(size_t)255;
        return p;
    };
    unsigned short* Qb = (unsigned short*)take((size_t)N_ROWS * DKV * 2);
    unsigned short* Kb = (unsigned short*)take((size_t)N_ROWS * DKV * 2);
    unsigned short* Vt = (unsigned short*)take((size_t)DKV * N_ROWS * 2);
    float*          Qf = (float*)take((size_t)N_ROWS * DKV * 4);

    // split=16, 512 kv per block = 2 chunks of KVS=256.
    int split = 16, nchunk = 2;
    const size_t per_split = (size_t)N_ROWS * 64 * 2 + (size_t)N_ROWS * 4 + 512;
    while (split > 1 && off + (size_t)split * per_split > ws_size) { split >>= 1; nchunk <<= 1; }

    unsigned short* PartOb = (unsigned short*)take((size_t)split * N_ROWS * 64 * 2);
    float*          PartL  = (float*)take((size_t)split * N_ROWS * 4);

    qkv_kernel<<<dim3(N_ROWS / 32), dim3(128), 0, stream>>>(
        x, Wq, bq, Wk, bk, Wv, bv, Qb, Kb, Vt, Qf);
    attn_kernel<<<dim3(N_ROWS / 256, split), dim3(512), 0, stream>>>(
        Qb, Kb, Vt, PartOb, PartL, nchunk);
    merge_kernel<<<dim3(N_ROWS * 32 / 256), dim3(256), 0, stream>>>(
        PartOb, PartL, Qf, out, split);
}